// Round 6
// baseline (321.590 us; speedup 1.0000x reference)
//
#include <hip/hip_runtime.h>

#define TB 2
#define TT 2048
#define TDIM 2048
#define NHEADS 16
#define KVHEADS 4
#define HD 128

typedef unsigned short u16;
typedef unsigned int u32;
typedef __attribute__((ext_vector_type(8))) short short8;
typedef __attribute__((ext_vector_type(4))) float float4_t;

__device__ __forceinline__ float b2f(u16 u) {
    union { u32 i; float f; } v; v.i = ((u32)u) << 16; return v.f;
}
__device__ __forceinline__ u16 f2b(float f) {
    union { float f; u32 i; } v; v.f = f;
    u32 r = (v.i + 0x7FFFu + ((v.i >> 16) & 1u)) >> 16;
    return (u16)r;
}
__device__ __forceinline__ u32 fbits(float f) {
    union { float f; u32 i; } v; v.f = f; return v.i;
}

// async global->LDS, 16B/lane; LDS dest must be wave-uniform base (+lane*16)
__device__ __forceinline__ void gl_lds16(const void* g, void* l) {
    __builtin_amdgcn_global_load_lds((const __attribute__((address_space(1))) void*)g,
                                     (__attribute__((address_space(3))) void*)l, 16, 0, 0);
}

// ---------------------------------------------------------------------------
// bf16 GEMM: C[M,N] = A[M,K] * B[K,N], B pre-transposed (BT is N x K, bf16).
// 128x128 tile, BK=64, 4 waves (2x2), m97 structure.
// ROPE: fused rotary embedding in the epilogue for Q|K columns (col < 2560);
// pair partner fetched via shfl_xor(1) (even/odd cols sit in adjacent lanes).
// ---------------------------------------------------------------------------
template <bool F32OUT, bool ROPE>
__global__ __launch_bounds__(256, 3)
void gemm_bt(const u16* __restrict__ A, const u16* __restrict__ BT,
             void* __restrict__ Cv, int M, int N, int K,
             const float* __restrict__ fc, const float* __restrict__ fs) {
    __shared__ __align__(16) u16 As[128 * 64];
    __shared__ __align__(16) u16 Bs[128 * 64];
    const int tid  = threadIdx.x;
    const int wave = tid >> 6, lane = tid & 63;
    const int quad = lane >> 4, l16 = lane & 15;
    const int wm = wave >> 1, wn = wave & 1;
    const int row0 = blockIdx.y * 128, col0 = blockIdx.x * 128;

    float4_t acc[4][4];
#pragma unroll
    for (int i = 0; i < 4; i++)
#pragma unroll
        for (int j = 0; j < 4; j++) acc[i][j] = (float4_t){0.f, 0.f, 0.f, 0.f};

    for (int kk = 0; kk < K; kk += 64) {
        __syncthreads();
#pragma unroll
        for (int i = 0; i < 4; i++) {
            int n = i * 256 + wave * 64 + lane;
            int r = n >> 3, c = (n & 7) ^ (r & 7);
            gl_lds16(A  + (size_t)(row0 + r) * K + kk + c * 8, &As[(i * 256 + wave * 64) * 8]);
            gl_lds16(BT + (size_t)(col0 + r) * K + kk + c * 8, &Bs[(i * 256 + wave * 64) * 8]);
        }
        __syncthreads();
#pragma unroll
        for (int ks = 0; ks < 2; ks++) {
            short8 af[4], bf[4];
#pragma unroll
            for (int mt = 0; mt < 4; mt++) {
                int m = wm * 64 + mt * 16 + l16;
                af[mt] = *(const short8*)&As[(m * 8 + ((ks * 4 + quad) ^ (l16 & 7))) * 8];
            }
#pragma unroll
            for (int nt = 0; nt < 4; nt++) {
                int n = wn * 64 + nt * 16 + l16;
                bf[nt] = *(const short8*)&Bs[(n * 8 + ((ks * 4 + quad) ^ (l16 & 7))) * 8];
            }
#pragma unroll
            for (int mt = 0; mt < 4; mt++)
#pragma unroll
                for (int nt = 0; nt < 4; nt++)
                    acc[mt][nt] = __builtin_amdgcn_mfma_f32_16x16x32_bf16(
                        af[mt], bf[nt], acc[mt][nt], 0, 0, 0);
        }
    }
    // epilogue: C/D layout col=lane&15, row=quad*4+reg  [m89/m91]
    const bool do_rope = ROPE && (col0 < 2560);
#pragma unroll
    for (int mt = 0; mt < 4; mt++)
#pragma unroll
        for (int nt = 0; nt < 4; nt++)
#pragma unroll
            for (int r = 0; r < 4; r++) {
                int row = row0 + wm * 64 + mt * 16 + quad * 4 + r;
                int col = col0 + wn * 64 + nt * 16 + l16;
                float v = acc[mt][nt][r];
                if (ROPE && do_rope) {
                    float other = __shfl_xor(v, 1, 64);
                    int t = row & (TT - 1);
                    int i0 = (col & (HD - 1)) >> 1;
                    float c = fc[t * 64 + i0], s = fs[t * 64 + i0];
                    v = (col & 1) ? fmaf(v, c, other * s) : fmaf(v, c, -other * s);
                }
                if (F32OUT)
                    ((float*)Cv)[(size_t)row * N + col] = v;
                else
                    ((u16*)Cv)[(size_t)row * N + col] = f2b(v);
            }
}

// ---------------------------------------------------------------------------
// fp32 (rows x cols) -> bf16 transposed (cols x rows)
// ---------------------------------------------------------------------------
__global__ void cvt_transpose(const float* __restrict__ in, u16* __restrict__ out,
                              int rows, int cols) {
    __shared__ u16 tile[32][33];
    int c0 = blockIdx.x * 32, r0 = blockIdx.y * 32;
    int tx = threadIdx.x & 31, ty = threadIdx.x >> 5;
#pragma unroll
    for (int i = 0; i < 4; i++)
        tile[ty + i * 8][tx] = f2b(in[(size_t)(r0 + ty + i * 8) * cols + c0 + tx]);
    __syncthreads();
#pragma unroll
    for (int i = 0; i < 4; i++)
        out[(size_t)(c0 + ty + i * 8) * rows + r0 + tx] = tile[tx][ty + i * 8];
}

// fp32 -> bf16 elementwise, 4 elems/thread
__global__ void cvt_bf16(const float* __restrict__ in, u16* __restrict__ out) {
    size_t i = ((size_t)blockIdx.x * 256 + threadIdx.x) * 4;
    float4 v = *(const float4*)(in + i);
    ushort4 o;
    o.x = f2b(v.x); o.y = f2b(v.y); o.z = f2b(v.z); o.w = f2b(v.w);
    *(ushort4*)(out + i) = o;
}

// V slice of QKV (bf16, cols 2560 + kv*128) -> Vt[b][kv][d][t] (bf16)
__global__ void transpose_v(const u16* __restrict__ QKV, u16* __restrict__ Vt) {
    int z = blockIdx.z, b = z >> 2, kv = z & 3;
    const u16* in = QKV + (size_t)b * TT * 3072 + 2560 + kv * HD;  // (t,d)
    u16* out = Vt + (size_t)z * HD * TT;                           // (d,t)
    __shared__ u16 tile[32][33];
    int t0 = blockIdx.x * 32, d0 = blockIdx.y * 32;
    int tx = threadIdx.x & 31, ty = threadIdx.x >> 5;
#pragma unroll
    for (int i = 0; i < 4; i++)
        tile[ty + i * 8][tx] = in[(size_t)(t0 + ty + i * 8) * 3072 + d0 + tx];
    __syncthreads();
#pragma unroll
    for (int i = 0; i < 4; i++)
        out[(size_t)(d0 + ty + i * 8) * TT + t0 + tx] = tile[tx][ty + i * 8];
}

// ---------------------------------------------------------------------------
// Causal flash attention v4: each WAVE processes 16 q-rows x TWO heads of the
// same KV group -> every staged K/V fragment feeds 2 MFMAs (GQA reuse),
// halving LDS-read bytes per FLOP (the v3 bottleneck: ~103 B/cyc/CU ~ LDS BW
// ceiling). Double-buffered staging; exp2-domain softmax; v_perm P-pack.
// Grid: (16 q-pairs, 8 head-pairs, 2 b) = 256 uniform blocks (66 iters each).
// ---------------------------------------------------------------------------
#define PSTR 72
__global__ __launch_bounds__(256, 1)
void attn(const u16* __restrict__ QKV, const u16* __restrict__ Vt,
          u16* __restrict__ O) {
    const int g  = blockIdx.x;      // q pair index 0..15
    const int yp = blockIdx.y;      // head-pair 0..7
    const int b  = blockIdx.z;
    const int kvh = yp >> 1;
    const int hb  = kvh * 4 + (yp & 1) * 2;  // heads hb, hb+1
    const int tid = threadIdx.x, w = tid >> 6, lane = tid & 63;
    const int quad = lane >> 4, l16 = lane & 15;

    __shared__ __align__(16) u16 Ks[2][64 * 128];   // [key][16 chunks] sw: c^(key&15)
    __shared__ __align__(16) u16 Vs[2][128 * 64];   // [d][8 chunks]    sw: c^(d&7)
    __shared__ __align__(16) u16 Ps[8][16 * PSTR];  // per (wave,head) strip

    const u16* Kbase = QKV + (size_t)b * TT * 3072 + 2048 + kvh * HD;
    const u16* Vbase = Vt + (size_t)(b * 4 + kvh) * HD * TT;
    const float Cl = 0.12753102474f;  // (1/sqrt(128)) * log2(e)

    auto stage = [&](int kt, int bb) {
#pragma unroll
        for (int i = 0; i < 4; i++) {
            int n = i * 256 + w * 64 + lane;
            int r = n >> 4, c = (n & 15) ^ (r & 15);
            gl_lds16(Kbase + (size_t)(kt * 64 + r) * 3072 + c * 8,
                     &Ks[bb][(i * 256 + w * 64) * 8]);
        }
#pragma unroll
        for (int i = 0; i < 4; i++) {
            int n = i * 256 + w * 64 + lane;
            int d = n >> 3, c = (n & 7) ^ (d & 7);
            gl_lds16(Vbase + (size_t)d * TT + kt * 64 + c * 8,
                     &Vs[bb][(i * 256 + w * 64) * 8]);
        }
    };

    for (int ph = 0; ph < 2; ph++) {
        const int qb = ph ? (31 - g) : g;
        __syncthreads();  // previous phase fully done before re-staging buf 0
        stage(0, 0);

        // Q fragments to registers for both heads
        short8 qf[2][4];
#pragma unroll
        for (int hd = 0; hd < 2; hd++) {
            const u16* Qrow = QKV + ((size_t)b * TT + qb * 64 + w * 16 + l16) * 3072
                              + (hb + hd) * HD;
#pragma unroll
            for (int ks = 0; ks < 4; ks++)
                qf[hd][ks] = *(const short8*)(Qrow + ks * 32 + quad * 8);
        }

        float4_t o[2][8];
#pragma unroll
        for (int hd = 0; hd < 2; hd++)
#pragma unroll
            for (int i = 0; i < 8; i++) o[hd][i] = (float4_t){0.f, 0.f, 0.f, 0.f};
        float mi[2] = {-1e30f, -1e30f}, li[2] = {0.f, 0.f};
        const int qg = qb * 64 + w * 16 + l16;  // this lane's q-row (S^T col)

        for (int kt = 0; kt <= qb; kt++) {
            const int cur = kt & 1;
            __syncthreads();                       // drains stage(kt)
            if (kt < qb) stage(kt + 1, cur ^ 1);   // prefetch under compute

            // S^T = K·Q^T for both heads: shared af, per-head qf
            float4_t st[2][4];
#pragma unroll
            for (int hd = 0; hd < 2; hd++)
#pragma unroll
                for (int nt = 0; nt < 4; nt++) st[hd][nt] = (float4_t){0.f, 0.f, 0.f, 0.f};
#pragma unroll
            for (int ks = 0; ks < 4; ks++) {
                short8 af[4];
#pragma unroll
                for (int nt = 0; nt < 4; nt++)
                    af[nt] = *(const short8*)&Ks[cur][((nt * 16 + l16) * 16 +
                                                      ((ks * 4 + quad) ^ l16)) * 8];
#pragma unroll
                for (int nt = 0; nt < 4; nt++) {
                    st[0][nt] = __builtin_amdgcn_mfma_f32_16x16x32_bf16(
                        af[nt], qf[0][ks], st[0][nt], 0, 0, 0);
                    st[1][nt] = __builtin_amdgcn_mfma_f32_16x16x32_bf16(
                        af[nt], qf[1][ks], st[1][nt], 0, 0, 0);
                }
            }

            // mask + softmax + pack, per head
            const bool diag = (kt == qb);
            float alpha[2];
#pragma unroll
            for (int hd = 0; hd < 2; hd++) {
                if (diag) {
#pragma unroll
                    for (int nt = 0; nt < 4; nt++)
#pragma unroll
                        for (int r = 0; r < 4; r++) {
                            int key = kt * 64 + nt * 16 + quad * 4 + r;
                            if (key > qg) st[hd][nt][r] = -3e38f;
                        }
                }
                float pm = -3e38f;
#pragma unroll
                for (int nt = 0; nt < 4; nt++)
#pragma unroll
                    for (int r = 0; r < 4; r++) pm = fmaxf(pm, st[hd][nt][r]);
                pm = fmaxf(pm, __shfl_xor(pm, 16, 64));
                pm = fmaxf(pm, __shfl_xor(pm, 32, 64));
                float mnew = fmaxf(mi[hd], pm);
                alpha[hd] = __builtin_amdgcn_exp2f((mi[hd] - mnew) * Cl);
                mi[hd] = mnew;
                const float mC = mnew * Cl;
                float rs = 0.f;
#pragma unroll
                for (int nt = 0; nt < 4; nt++)
#pragma unroll
                    for (int r = 0; r < 4; r++) {
                        float e = __builtin_amdgcn_exp2f(fmaf(st[hd][nt][r], Cl, -mC));
                        st[hd][nt][r] = e;
                        rs += e;
                    }
                rs += __shfl_xor(rs, 16, 64);
                rs += __shfl_xor(rs, 32, 64);
                li[hd] = li[hd] * alpha[hd] + rs;

                // P -> strip (truncation-pack via v_perm, b64 writes)
#pragma unroll
                for (int nt = 0; nt < 4; nt++) {
                    uint2 pk;
                    pk.x = __builtin_amdgcn_perm(fbits(st[hd][nt][1]), fbits(st[hd][nt][0]), 0x07060302u);
                    pk.y = __builtin_amdgcn_perm(fbits(st[hd][nt][3]), fbits(st[hd][nt][2]), 0x07060302u);
                    *(uint2*)&Ps[w * 2 + hd][l16 * PSTR + nt * 16 + quad * 4] = pk;
                }
                // rescale O (o rows are q=quad*4+r -> alpha from lane q)
                float a_o[4];
#pragma unroll
                for (int r = 0; r < 4; r++) a_o[r] = __shfl(alpha[hd], quad * 4 + r, 64);
#pragma unroll
                for (int n2 = 0; n2 < 8; n2++)
#pragma unroll
                    for (int r = 0; r < 4; r++) o[hd][n2][r] *= a_o[r];
            }

            // O += P·V for both heads: shared bv, per-head ap
#pragma unroll
            for (int ks2 = 0; ks2 < 2; ks2++) {
                short8 apA = *(const short8*)&Ps[w * 2 + 0][l16 * PSTR + ks2 * 32 + quad * 8];
                short8 apB = *(const short8*)&Ps[w * 2 + 1][l16 * PSTR + ks2 * 32 + quad * 8];
#pragma unroll
                for (int n2 = 0; n2 < 8; n2++) {
                    short8 bv = *(const short8*)&Vs[cur][((n2 * 16 + l16) * 8 +
                                                         ((ks2 * 4 + quad) ^ (l16 & 7))) * 8];
                    o[0][n2] = __builtin_amdgcn_mfma_f32_16x16x32_bf16(apA, bv, o[0][n2], 0, 0, 0);
                    o[1][n2] = __builtin_amdgcn_mfma_f32_16x16x32_bf16(apB, bv, o[1][n2], 0, 0, 0);
                }
            }
        }

        // epilogue: both heads
#pragma unroll
        for (int hd = 0; hd < 2; hd++) {
            float l_o[4];
#pragma unroll
            for (int r = 0; r < 4; r++) l_o[r] = __shfl(li[hd], quad * 4 + r, 64);
            u16* Ob2 = O + ((size_t)b * TT + qb * 64 + w * 16) * TDIM + (hb + hd) * HD;
#pragma unroll
            for (int n2 = 0; n2 < 8; n2++)
#pragma unroll
                for (int r = 0; r < 4; r++)
                    Ob2[(size_t)(quad * 4 + r) * TDIM + n2 * 16 + l16] =
                        f2b(o[hd][n2][r] / l_o[r]);
        }
    }
}

// ---------------------------------------------------------------------------
extern "C" void kernel_launch(void* const* d_in, const int* in_sizes, int n_in,
                              void* d_out, int out_size, void* d_ws, size_t ws_size,
                              hipStream_t stream) {
    const float* x  = (const float*)d_in[0];
    const float* fc = (const float*)d_in[1];
    const float* fs = (const float*)d_in[2];
    const float* wq = (const float*)d_in[3];
    const float* wk = (const float*)d_in[4];
    const float* wv = (const float*)d_in[5];
    const float* wo = (const float*)d_in[6];
    float* out = (float*)d_out;

    char* ws = (char*)d_ws;
    size_t off = 0;
    auto alloc = [&](size_t bytes) -> void* {
        void* p = ws + off;
        off += (bytes + 255) & ~(size_t)255;
        return p;
    };
    u16* xb  = (u16*)alloc((size_t)4096 * 2048 * 2);  // x in bf16
    u16* WT  = (u16*)alloc((size_t)3072 * 2048 * 2);  // [wqT|wkT|wvT] N x K bf16
    u16* woT = (u16*)alloc((size_t)2048 * 2048 * 2);
    u16* QKV = (u16*)alloc((size_t)4096 * 3072 * 2);  // [Q|K|V] fused bf16 (roped)
    u16* Vtb = (u16*)alloc((size_t)4096 * 512 * 2);   // V^T per (b,kv): [d][t]
    u16* Ob  = (u16*)alloc((size_t)4096 * 2048 * 2);  // attention output bf16

    dim3 blk(256);
    cvt_bf16<<<dim3(8192), blk, 0, stream>>>(x, xb);
    cvt_transpose<<<dim3(64, 64), blk, 0, stream>>>(wq, WT, 2048, 2048);
    cvt_transpose<<<dim3(16, 64), blk, 0, stream>>>(wk, WT + (size_t)2048 * 2048, 2048, 512);
    cvt_transpose<<<dim3(16, 64), blk, 0, stream>>>(wv, WT + (size_t)2560 * 2048, 2048, 512);
    cvt_transpose<<<dim3(64, 64), blk, 0, stream>>>(wo, woT, 2048, 2048);
    // fused QKV projection with RoPE applied in the epilogue (Q|K cols only)
    gemm_bt<false, true><<<dim3(24, 32), blk, 0, stream>>>(
        xb, WT, QKV, 4096, 3072, 2048, fc, fs);
    transpose_v<<<dim3(64, 4, 8), blk, 0, stream>>>(QKV, Vtb);
    attn<<<dim3(16, 8, 2), blk, 0, stream>>>(QKV, Vtb, Ob);
    gemm_bt<true, false><<<dim3(16, 32), blk, 0, stream>>>(
        Ob, woT, out, 4096, 2048, 2048, nullptr, nullptr);
}

// Round 7
// 291.441 us; speedup vs baseline: 1.1034x; 1.1034x over previous
//
#include <hip/hip_runtime.h>

#define TB 2
#define TT 2048
#define TDIM 2048
#define NHEADS 16
#define KVHEADS 4
#define HD 128

typedef unsigned short u16;
typedef unsigned int u32;
typedef __attribute__((ext_vector_type(8))) short short8;
typedef __attribute__((ext_vector_type(4))) float float4_t;

__device__ __forceinline__ float b2f(u16 u) {
    union { u32 i; float f; } v; v.i = ((u32)u) << 16; return v.f;
}
__device__ __forceinline__ u16 f2b(float f) {
    union { float f; u32 i; } v; v.f = f;
    u32 r = (v.i + 0x7FFFu + ((v.i >> 16) & 1u)) >> 16;
    return (u16)r;
}
__device__ __forceinline__ u32 fbits(float f) {
    union { float f; u32 i; } v; v.f = f; return v.i;
}

// async global->LDS, 16B/lane; LDS dest must be wave-uniform base (+lane*16)
__device__ __forceinline__ void gl_lds16(const void* g, void* l) {
    __builtin_amdgcn_global_load_lds((const __attribute__((address_space(1))) void*)g,
                                     (__attribute__((address_space(3))) void*)l, 16, 0, 0);
}

// ---------------------------------------------------------------------------
// bf16 GEMM: C[M,N] = A[M,K] * B[K,N], B pre-transposed (BT is N x K, bf16).
// 128x128 tile, BK=64, 4 waves (2x2), m97 structure. Optional fused RoPE.
// ---------------------------------------------------------------------------
template <bool F32OUT, bool ROPE>
__global__ __launch_bounds__(256, 3)
void gemm_bt(const u16* __restrict__ A, const u16* __restrict__ BT,
             void* __restrict__ Cv, int M, int N, int K,
             const float* __restrict__ fc, const float* __restrict__ fs) {
    __shared__ __align__(16) u16 As[128 * 64];
    __shared__ __align__(16) u16 Bs[128 * 64];
    const int tid  = threadIdx.x;
    const int wave = tid >> 6, lane = tid & 63;
    const int quad = lane >> 4, l16 = lane & 15;
    const int wm = wave >> 1, wn = wave & 1;
    const int row0 = blockIdx.y * 128, col0 = blockIdx.x * 128;

    float4_t acc[4][4];
#pragma unroll
    for (int i = 0; i < 4; i++)
#pragma unroll
        for (int j = 0; j < 4; j++) acc[i][j] = (float4_t){0.f, 0.f, 0.f, 0.f};

    for (int kk = 0; kk < K; kk += 64) {
        __syncthreads();
#pragma unroll
        for (int i = 0; i < 4; i++) {
            int n = i * 256 + wave * 64 + lane;
            int r = n >> 3, c = (n & 7) ^ (r & 7);
            gl_lds16(A  + (size_t)(row0 + r) * K + kk + c * 8, &As[(i * 256 + wave * 64) * 8]);
            gl_lds16(BT + (size_t)(col0 + r) * K + kk + c * 8, &Bs[(i * 256 + wave * 64) * 8]);
        }
        __syncthreads();
#pragma unroll
        for (int ks = 0; ks < 2; ks++) {
            short8 af[4], bf[4];
#pragma unroll
            for (int mt = 0; mt < 4; mt++) {
                int m = wm * 64 + mt * 16 + l16;
                af[mt] = *(const short8*)&As[(m * 8 + ((ks * 4 + quad) ^ (l16 & 7))) * 8];
            }
#pragma unroll
            for (int nt = 0; nt < 4; nt++) {
                int n = wn * 64 + nt * 16 + l16;
                bf[nt] = *(const short8*)&Bs[(n * 8 + ((ks * 4 + quad) ^ (l16 & 7))) * 8];
            }
#pragma unroll
            for (int mt = 0; mt < 4; mt++)
#pragma unroll
                for (int nt = 0; nt < 4; nt++)
                    acc[mt][nt] = __builtin_amdgcn_mfma_f32_16x16x32_bf16(
                        af[mt], bf[nt], acc[mt][nt], 0, 0, 0);
        }
    }
    // epilogue: C/D layout col=lane&15, row=quad*4+reg  [m89/m91]
    const bool do_rope = ROPE && (col0 < 2560);
#pragma unroll
    for (int mt = 0; mt < 4; mt++)
#pragma unroll
        for (int nt = 0; nt < 4; nt++)
#pragma unroll
            for (int r = 0; r < 4; r++) {
                int row = row0 + wm * 64 + mt * 16 + quad * 4 + r;
                int col = col0 + wn * 64 + nt * 16 + l16;
                float v = acc[mt][nt][r];
                if (ROPE && do_rope) {
                    float other = __shfl_xor(v, 1, 64);
                    int t = row & (TT - 1);
                    int i0 = (col & (HD - 1)) >> 1;
                    float c = fc[t * 64 + i0], s = fs[t * 64 + i0];
                    v = (col & 1) ? fmaf(v, c, other * s) : fmaf(v, c, -other * s);
                }
                if (F32OUT)
                    ((float*)Cv)[(size_t)row * N + col] = v;
                else
                    ((u16*)Cv)[(size_t)row * N + col] = f2b(v);
            }
}

// ---------------------------------------------------------------------------
// All four weight transposes (fp32 KxN -> bf16 NxK) in one launch.
// grid (160, 64): x<64 wq | x<80 wk | x<96 wv | else wo.
// ---------------------------------------------------------------------------
__global__ void cvt_transpose4(const float* __restrict__ wq, const float* __restrict__ wk,
                               const float* __restrict__ wv, const float* __restrict__ wo,
                               u16* __restrict__ WT, u16* __restrict__ woT) {
    int bx = blockIdx.x;
    const float* in; u16* out; int cols, cx;
    if (bx < 64)      { in = wq; out = WT;                         cols = 2048; cx = bx; }
    else if (bx < 80) { in = wk; out = WT + (size_t)2048 * 2048;   cols = 512;  cx = bx - 64; }
    else if (bx < 96) { in = wv; out = WT + (size_t)2560 * 2048;   cols = 512;  cx = bx - 80; }
    else              { in = wo; out = woT;                        cols = 2048; cx = bx - 96; }
    const int rows = 2048;
    __shared__ u16 tile[32][33];
    int c0 = cx * 32, r0 = blockIdx.y * 32;
    int tx = threadIdx.x & 31, ty = threadIdx.x >> 5;
#pragma unroll
    for (int i = 0; i < 4; i++)
        tile[ty + i * 8][tx] = f2b(in[(size_t)(r0 + ty + i * 8) * cols + c0 + tx]);
    __syncthreads();
#pragma unroll
    for (int i = 0; i < 4; i++)
        out[(size_t)(c0 + ty + i * 8) * rows + r0 + tx] = tile[tx][ty + i * 8];
}

// fp32 -> bf16 elementwise, 4 elems/thread
__global__ void cvt_bf16(const float* __restrict__ in, u16* __restrict__ out) {
    size_t i = ((size_t)blockIdx.x * 256 + threadIdx.x) * 4;
    float4 v = *(const float4*)(in + i);
    ushort4 o;
    o.x = f2b(v.x); o.y = f2b(v.y); o.z = f2b(v.z); o.w = f2b(v.w);
    *(ushort4*)(out + i) = o;
}

// V slice of QKV (bf16, cols 2560 + kv*128) -> Vt[b][kv][d][t] (bf16)
__global__ void transpose_v(const u16* __restrict__ QKV, u16* __restrict__ Vt) {
    int z = blockIdx.z, b = z >> 2, kv = z & 3;
    const u16* in = QKV + (size_t)b * TT * 3072 + 2560 + kv * HD;  // (t,d)
    u16* out = Vt + (size_t)z * HD * TT;                           // (d,t)
    __shared__ u16 tile[32][33];
    int t0 = blockIdx.x * 32, d0 = blockIdx.y * 32;
    int tx = threadIdx.x & 31, ty = threadIdx.x >> 5;
#pragma unroll
    for (int i = 0; i < 4; i++)
        tile[ty + i * 8][tx] = in[(size_t)(t0 + ty + i * 8) * 3072 + d0 + tx];
    __syncthreads();
#pragma unroll
    for (int i = 0; i < 4; i++)
        out[(size_t)(d0 + ty + i * 8) * TT + t0 + tx] = tile[tx][ty + i * 8];
}

// ---------------------------------------------------------------------------
// Causal flash attention v5: v4's register-level GQA reuse (wave = 16 q-rows
// x 2 heads; each staged K/V fragment feeds 2 MFMAs) with occupancy restored:
// grid = 512 blocks (one q-tile each) and LDS 66 KB -> 2 blocks/CU, 8 waves.
// K double-buffered (prefetch under PV + next S^T); V single-buffered, staged
// at iter top and drained by a 2nd barrier right before PV.
// Load balance: qb = b ? 31-x : x -> co-scheduled pairs (i, i+256) sum to 33.
// ---------------------------------------------------------------------------
#define PSTR 72
__global__ __launch_bounds__(256, 2)
void attn(const u16* __restrict__ QKV, const u16* __restrict__ Vt,
          u16* __restrict__ O) {
    const int x  = blockIdx.x;      // q-tile selector 0..31
    const int y  = blockIdx.y;      // (b, head-pair): b = y>>3, hp = y&7
    const int b  = y >> 3;
    const int hp = y & 7;
    const int kvh = hp >> 1;
    const int hb  = kvh * 4 + (hp & 1) * 2;   // heads hb, hb+1
    const int qb  = b ? (31 - x) : x;         // anti-correlated sizes
    const int tid = threadIdx.x, w = tid >> 6, lane = tid & 63;
    const int quad = lane >> 4, l16 = lane & 15;

    __shared__ __align__(16) u16 Ks[2][64 * 128];   // [key][16 chunks] sw: c^(key&15)
    __shared__ __align__(16) u16 Vs[128 * 64];      // [d][8 chunks]    sw: c^(d&7)
    __shared__ __align__(16) u16 Ps[8][16 * PSTR];  // per (wave,head) strip

    const u16* Kbase = QKV + (size_t)b * TT * 3072 + 2048 + kvh * HD;
    const u16* Vbase = Vt + (size_t)(b * 4 + kvh) * HD * TT;
    const float Cl = 0.12753102474f;  // (1/sqrt(128)) * log2(e)

    auto stageK = [&](int kt, int bb) {
#pragma unroll
        for (int i = 0; i < 4; i++) {
            int n = i * 256 + w * 64 + lane;
            int r = n >> 4, c = (n & 15) ^ (r & 15);
            gl_lds16(Kbase + (size_t)(kt * 64 + r) * 3072 + c * 8,
                     &Ks[bb][(i * 256 + w * 64) * 8]);
        }
    };
    auto stageV = [&](int kt) {
#pragma unroll
        for (int i = 0; i < 4; i++) {
            int n = i * 256 + w * 64 + lane;
            int d = n >> 3, c = (n & 7) ^ (d & 7);
            gl_lds16(Vbase + (size_t)d * TT + kt * 64 + c * 8,
                     &Vs[(i * 256 + w * 64) * 8]);
        }
    };

    stageK(0, 0);

    // Q fragments to registers for both heads (B-layout: l16 = q-row)
    short8 qf[2][4];
#pragma unroll
    for (int hd = 0; hd < 2; hd++) {
        const u16* Qrow = QKV + ((size_t)b * TT + qb * 64 + w * 16 + l16) * 3072
                          + (hb + hd) * HD;
#pragma unroll
        for (int ks = 0; ks < 4; ks++)
            qf[hd][ks] = *(const short8*)(Qrow + ks * 32 + quad * 8);
    }

    float4_t o[2][8];
#pragma unroll
    for (int hd = 0; hd < 2; hd++)
#pragma unroll
        for (int i = 0; i < 8; i++) o[hd][i] = (float4_t){0.f, 0.f, 0.f, 0.f};
    float mi[2] = {-1e30f, -1e30f}, li[2] = {0.f, 0.f};
    const int qg = qb * 64 + w * 16 + l16;  // this lane's q-row (S^T col)

    for (int kt = 0; kt <= qb; kt++) {
        const int cur = kt & 1;
        __syncthreads();        // B1: K[kt] landed; prev PV done reading Vs
        stageV(kt);             // async; lands under S^T + softmax

        // S^T = K·Q^T for both heads: shared af, per-head qf
        float4_t st[2][4];
#pragma unroll
        for (int hd = 0; hd < 2; hd++)
#pragma unroll
            for (int nt = 0; nt < 4; nt++) st[hd][nt] = (float4_t){0.f, 0.f, 0.f, 0.f};
#pragma unroll
        for (int ks = 0; ks < 4; ks++) {
            short8 af[4];
#pragma unroll
            for (int nt = 0; nt < 4; nt++)
                af[nt] = *(const short8*)&Ks[cur][((nt * 16 + l16) * 16 +
                                                  ((ks * 4 + quad) ^ l16)) * 8];
#pragma unroll
            for (int nt = 0; nt < 4; nt++) {
                st[0][nt] = __builtin_amdgcn_mfma_f32_16x16x32_bf16(
                    af[nt], qf[0][ks], st[0][nt], 0, 0, 0);
                st[1][nt] = __builtin_amdgcn_mfma_f32_16x16x32_bf16(
                    af[nt], qf[1][ks], st[1][nt], 0, 0, 0);
            }
        }

        // mask + softmax + pack, per head
        const bool diag = (kt == qb);
        float alpha[2];
#pragma unroll
        for (int hd = 0; hd < 2; hd++) {
            if (diag) {
#pragma unroll
                for (int nt = 0; nt < 4; nt++)
#pragma unroll
                    for (int r = 0; r < 4; r++) {
                        int key = kt * 64 + nt * 16 + quad * 4 + r;
                        if (key > qg) st[hd][nt][r] = -3e38f;
                    }
            }
            float pm = -3e38f;
#pragma unroll
            for (int nt = 0; nt < 4; nt++)
#pragma unroll
                for (int r = 0; r < 4; r++) pm = fmaxf(pm, st[hd][nt][r]);
            pm = fmaxf(pm, __shfl_xor(pm, 16, 64));
            pm = fmaxf(pm, __shfl_xor(pm, 32, 64));
            float mnew = fmaxf(mi[hd], pm);
            alpha[hd] = __builtin_amdgcn_exp2f((mi[hd] - mnew) * Cl);
            mi[hd] = mnew;
            const float mC = mnew * Cl;
            float rs = 0.f;
#pragma unroll
            for (int nt = 0; nt < 4; nt++)
#pragma unroll
                for (int r = 0; r < 4; r++) {
                    float e = __builtin_amdgcn_exp2f(fmaf(st[hd][nt][r], Cl, -mC));
                    st[hd][nt][r] = e;
                    rs += e;
                }
            rs += __shfl_xor(rs, 16, 64);
            rs += __shfl_xor(rs, 32, 64);
            li[hd] = li[hd] * alpha[hd] + rs;

            // P -> strip (truncation-pack via v_perm, b64 writes)
#pragma unroll
            for (int nt = 0; nt < 4; nt++) {
                uint2 pk;
                pk.x = __builtin_amdgcn_perm(fbits(st[hd][nt][1]), fbits(st[hd][nt][0]), 0x07060302u);
                pk.y = __builtin_amdgcn_perm(fbits(st[hd][nt][3]), fbits(st[hd][nt][2]), 0x07060302u);
                *(uint2*)&Ps[w * 2 + hd][l16 * PSTR + nt * 16 + quad * 4] = pk;
            }
            // rescale O (o rows are q=quad*4+r -> alpha from lane q)
            float a_o[4];
#pragma unroll
            for (int r = 0; r < 4; r++) a_o[r] = __shfl(alpha[hd], quad * 4 + r, 64);
#pragma unroll
            for (int n2 = 0; n2 < 8; n2++)
#pragma unroll
                for (int r = 0; r < 4; r++) o[hd][n2][r] *= a_o[r];
        }

        __syncthreads();                       // B2: V[kt] landed in Vs
        if (kt < qb) stageK(kt + 1, cur ^ 1);  // prefetch under PV + next smax

        // O += P·V for both heads: shared bv, per-head ap
#pragma unroll
        for (int ks2 = 0; ks2 < 2; ks2++) {
            short8 apA = *(const short8*)&Ps[w * 2 + 0][l16 * PSTR + ks2 * 32 + quad * 8];
            short8 apB = *(const short8*)&Ps[w * 2 + 1][l16 * PSTR + ks2 * 32 + quad * 8];
#pragma unroll
            for (int n2 = 0; n2 < 8; n2++) {
                short8 bv = *(const short8*)&Vs[((n2 * 16 + l16) * 8 +
                                                ((ks2 * 4 + quad) ^ (l16 & 7))) * 8];
                o[0][n2] = __builtin_amdgcn_mfma_f32_16x16x32_bf16(apA, bv, o[0][n2], 0, 0, 0);
                o[1][n2] = __builtin_amdgcn_mfma_f32_16x16x32_bf16(apB, bv, o[1][n2], 0, 0, 0);
            }
        }
    }

    // epilogue: both heads
#pragma unroll
    for (int hd = 0; hd < 2; hd++) {
        float l_o[4];
#pragma unroll
        for (int r = 0; r < 4; r++) l_o[r] = __shfl(li[hd], quad * 4 + r, 64);
        u16* Ob2 = O + ((size_t)b * TT + qb * 64 + w * 16) * TDIM + (hb + hd) * HD;
#pragma unroll
        for (int n2 = 0; n2 < 8; n2++)
#pragma unroll
            for (int r = 0; r < 4; r++)
                Ob2[(size_t)(quad * 4 + r) * TDIM + n2 * 16 + l16] =
                    f2b(o[hd][n2][r] / l_o[r]);
    }
}

// ---------------------------------------------------------------------------
extern "C" void kernel_launch(void* const* d_in, const int* in_sizes, int n_in,
                              void* d_out, int out_size, void* d_ws, size_t ws_size,
                              hipStream_t stream) {
    const float* x  = (const float*)d_in[0];
    const float* fc = (const float*)d_in[1];
    const float* fs = (const float*)d_in[2];
    const float* wq = (const float*)d_in[3];
    const float* wk = (const float*)d_in[4];
    const float* wv = (const float*)d_in[5];
    const float* wo = (const float*)d_in[6];
    float* out = (float*)d_out;

    char* ws = (char*)d_ws;
    size_t off = 0;
    auto alloc = [&](size_t bytes) -> void* {
        void* p = ws + off;
        off += (bytes + 255) & ~(size_t)255;
        return p;
    };
    u16* xb  = (u16*)alloc((size_t)4096 * 2048 * 2);  // x in bf16
    u16* WT  = (u16*)alloc((size_t)3072 * 2048 * 2);  // [wqT|wkT|wvT] N x K bf16
    u16* woT = (u16*)alloc((size_t)2048 * 2048 * 2);
    u16* QKV = (u16*)alloc((size_t)4096 * 3072 * 2);  // [Q|K|V] fused bf16 (roped)
    u16* Vtb = (u16*)alloc((size_t)4096 * 512 * 2);   // V^T per (b,kv): [d][t]
    u16* Ob  = (u16*)alloc((size_t)4096 * 2048 * 2);  // attention output bf16

    dim3 blk(256);
    cvt_bf16<<<dim3(8192), blk, 0, stream>>>(x, xb);
    cvt_transpose4<<<dim3(160, 64), blk, 0, stream>>>(wq, wk, wv, wo, WT, woT);
    // fused QKV projection with RoPE applied in the epilogue (Q|K cols only)
    gemm_bt<false, true><<<dim3(24, 32), blk, 0, stream>>>(
        xb, WT, QKV, 4096, 3072, 2048, fc, fs);
    transpose_v<<<dim3(64, 4, 8), blk, 0, stream>>>(QKV, Vtb);
    attn<<<dim3(32, 16), blk, 0, stream>>>(QKV, Vtb, Ob);
    gemm_bt<true, false><<<dim3(16, 32), blk, 0, stream>>>(
        Ob, woT, out, 4096, 2048, 2048, nullptr, nullptr);
}